// Round 1
// baseline (15817.908 us; speedup 1.0000x reference)
//
#include <hip/hip_runtime.h>
#include <math.h>

#define B   64
#define NQ  1024
#define DM  1024
#define H   16
#define D   64
#define TL  77
#define IL  256
#define NREL 33
#define SCALE 0.125f

// ---------------------------------------------------------------------------
// Generic fp32 tiled GEMM: C[M,N] = A_rows @ W[K,N] (+bias)
// A rows are addressed as: b = r / rows_per_batch, t = r % rows_per_batch,
// ptr = A + b*batch_stride + (row_offset + t)*K   (lets us slice context).
// BM=BN=64, BK=16, 256 threads, 4x4 micro-tile per thread.
// ---------------------------------------------------------------------------
__global__ __launch_bounds__(256)
void gemm_kernel(const float* __restrict__ A, const float* __restrict__ W,
                 const float* __restrict__ bias, float* __restrict__ C,
                 int rows_per_batch, long long batch_stride, int row_offset,
                 int N, int K)
{
    __shared__ float As[16][68];   // [k][m], padded to 68 for bank spread + 16B align
    __shared__ float Ws[16][64];   // [k][n]

    const int tid = threadIdx.x;
    const int tx = tid & 15, ty = tid >> 4;
    const int n0 = blockIdx.x * 64;
    const int m0 = blockIdx.y * 64;

    // Hoist per-thread A row base addresses (4 rows staged per thread)
    long long arow[4];
#pragma unroll
    for (int it = 0; it < 4; ++it) {
        int r  = it * 16 + ty;          // row within tile
        int gr = m0 + r;                // global row
        int bb = gr / rows_per_batch;
        int t  = gr - bb * rows_per_batch;
        arow[it] = (long long)bb * batch_stride + (long long)(row_offset + t) * K;
    }
    const int wk = tid >> 6;            // W stage: k sub-index
    const int wn = tid & 63;

    float c[4][4] = {};

    for (int kk = 0; kk < K; kk += 16) {
        // stage A tile (64 rows x 16 k), transposed into As[k][m]
#pragma unroll
        for (int it = 0; it < 4; ++it) {
            As[tx][it * 16 + ty] = A[arow[it] + kk + tx];
        }
        // stage W tile (16 k x 64 n)
#pragma unroll
        for (int it = 0; it < 4; ++it) {
            int k = it * 4 + wk;
            Ws[k][wn] = W[(long long)(kk + k) * N + n0 + wn];
        }
        __syncthreads();

#pragma unroll
        for (int k = 0; k < 16; ++k) {
            float a[4], bb[4];
#pragma unroll
            for (int i = 0; i < 4; ++i) a[i]  = As[k][ty * 4 + i];
#pragma unroll
            for (int j = 0; j < 4; ++j) bb[j] = Ws[k][tx * 4 + j];
#pragma unroll
            for (int i = 0; i < 4; ++i)
#pragma unroll
                for (int j = 0; j < 4; ++j)
                    c[i][j] += a[i] * bb[j];
        }
        __syncthreads();
    }

    // write back
#pragma unroll
    for (int i = 0; i < 4; ++i) {
        long long row = (long long)(m0 + ty * 4 + i) * N + n0;
#pragma unroll
        for (int j = 0; j < 4; ++j) {
            int n = tx * 4 + j;
            float v = c[i][j];
            if (bias) v += bias[n0 + n];
            C[row + n] = v;
        }
    }
}

// ---------------------------------------------------------------------------
// Fused attention: for each (b, h, query-tile of 64):
//   text branch: logits over 77 keys + rel-K bias, online softmax,
//                out = attn@(v + rel_v[idx])
//   image branch: logits over 256 keys, softmax, out += attn@v_ip
// Block = 256 threads = 4 waves; each wave owns 16 queries (one at a time).
// lane = key for logit phase, lane = dim for PV phase.
// ---------------------------------------------------------------------------
__global__ __launch_bounds__(256)
void attn_kernel(const float* __restrict__ q,  const float* __restrict__ kt,
                 const float* __restrict__ vt, const float* __restrict__ ki,
                 const float* __restrict__ vi, const float* __restrict__ relk,
                 const float* __restrict__ relv, float* __restrict__ oi)
{
    const int bh = blockIdx.y;
    const int b  = bh >> 4;
    const int h  = bh & 15;
    const int i0 = blockIdx.x * 64;
    const int tid  = threadIdx.x;
    const int w    = tid >> 6;
    const int lane = tid & 63;

    __shared__ float q_s[64][64];      // [query][d]  (broadcast reads only)
    __shared__ float k_s[64][65];      // [key][d]    padded: lane indexes rows
    __shared__ float v_s[64][64];      // [key][d]    row-uniform reads
    __shared__ float rk_s[NREL][65];   // padded: lane indexes rows
    __shared__ float rv_s[NREL][64];   // row-uniform reads

    // stage q tile + rel tables
    for (int e = tid; e < 64 * 64; e += 256) {
        int r = e >> 6, d = e & 63;
        q_s[r][d] = q[((long long)(b * NQ + i0 + r)) * DM + h * D + d];
    }
    for (int e = tid; e < NREL * D; e += 256) {
        int r = e >> 6, d = e & 63;
        rk_s[r][d] = relk[e];
        rv_s[r][d] = relv[e];
    }

    float m[16], l[16], acc[16], otx[16];
#pragma unroll
    for (int t = 0; t < 16; ++t) { m[t] = -INFINITY; l[t] = 0.f; acc[t] = 0.f; }

    // ---------------- text branch (77 keys, with rel) ----------------
    for (int c0 = 0; c0 < TL; c0 += 64) {
        int cnt = (TL - c0 < 64) ? (TL - c0) : 64;
        __syncthreads();
        for (int e = tid; e < cnt * 64; e += 256) {
            int r = e >> 6, d = e & 63;
            long long g = ((long long)(b * TL + c0 + r)) * DM + h * D + d;
            k_s[r][d] = kt[g];
            v_s[r][d] = vt[g];
        }
        __syncthreads();

        const bool valid = lane < cnt;
        const int  jg    = c0 + lane;
#pragma unroll
        for (int t = 0; t < 16; ++t) {
            const int qi = w * 16 + t;
            const int ig = i0 + qi;
            int dist = jg - ig;
            int idx  = min(max(dist, -16), 16) + 16;
            float s = 0.f, s2 = 0.f;
#pragma unroll 4
            for (int d = 0; d < 64; ++d) {
                float qd = q_s[qi][d];
                s  += qd * k_s[lane][d];
                s2 += qd * rk_s[idx][d];
            }
            float logit = valid ? (s + s2) * SCALE : -INFINITY;
            float cmax = logit;
#pragma unroll
            for (int off = 32; off >= 1; off >>= 1)
                cmax = fmaxf(cmax, __shfl_xor(cmax, off));
            float mn = fmaxf(m[t], cmax);
            float alpha = __expf(m[t] - mn);
            float p = valid ? __expf(logit - mn) : 0.f;
            float ps = p;
#pragma unroll
            for (int off = 32; off >= 1; off >>= 1)
                ps += __shfl_xor(ps, off);
            l[t] = l[t] * alpha + ps;
            acc[t] *= alpha;
            m[t] = mn;
#pragma unroll 4
            for (int jj = 0; jj < 64; ++jj) {
                if (jj >= cnt) break;
                float pj = __shfl(p, jj);
                int dist2 = (c0 + jj) - ig;
                int idx2  = min(max(dist2, -16), 16) + 16;
                acc[t] += pj * (v_s[jj][lane] + rv_s[idx2][lane]);
            }
        }
    }
#pragma unroll
    for (int t = 0; t < 16; ++t) {
        otx[t] = acc[t] / l[t];
        m[t] = -INFINITY; l[t] = 0.f; acc[t] = 0.f;
    }

    // ---------------- image branch (256 keys, no rel) ----------------
    for (int c0 = 0; c0 < IL; c0 += 64) {
        __syncthreads();
        for (int e = tid; e < 64 * 64; e += 256) {
            int r = e >> 6, d = e & 63;
            long long g = ((long long)(b * IL + c0 + r)) * DM + h * D + d;
            k_s[r][d] = ki[g];
            v_s[r][d] = vi[g];
        }
        __syncthreads();

#pragma unroll
        for (int t = 0; t < 16; ++t) {
            const int qi = w * 16 + t;
            float s = 0.f;
#pragma unroll 4
            for (int d = 0; d < 64; ++d) {
                float qd = q_s[qi][d];
                s += qd * k_s[lane][d];
            }
            float logit = s * SCALE;
            float cmax = logit;
#pragma unroll
            for (int off = 32; off >= 1; off >>= 1)
                cmax = fmaxf(cmax, __shfl_xor(cmax, off));
            float mn = fmaxf(m[t], cmax);
            float alpha = __expf(m[t] - mn);
            float p = __expf(logit - mn);
            float ps = p;
#pragma unroll
            for (int off = 32; off >= 1; off >>= 1)
                ps += __shfl_xor(ps, off);
            l[t] = l[t] * alpha + ps;
            acc[t] *= alpha;
            m[t] = mn;
#pragma unroll 4
            for (int jj = 0; jj < 64; ++jj) {
                float pj = __shfl(p, jj);
                acc[t] += pj * v_s[jj][lane];
            }
        }
    }

    // write out_inner[b, i, h*64 + lane]
#pragma unroll
    for (int t = 0; t < 16; ++t) {
        const int qi = w * 16 + t;
        oi[((long long)(b * NQ + i0 + qi)) * DM + h * D + lane] = otx[t] + acc[t] / l[t];
    }
}

// ---------------------------------------------------------------------------
extern "C" void kernel_launch(void* const* d_in, const int* in_sizes, int n_in,
                              void* d_out, int out_size, void* d_ws, size_t ws_size,
                              hipStream_t stream)
{
    const float* x    = (const float*)d_in[0];
    const float* ctx  = (const float*)d_in[1];
    const float* Wq   = (const float*)d_in[2];
    const float* Wk   = (const float*)d_in[3];
    const float* Wv   = (const float*)d_in[4];
    const float* Wkip = (const float*)d_in[5];
    const float* Wvip = (const float*)d_in[6];
    const float* Wout = (const float*)d_in[7];
    const float* bout = (const float*)d_in[8];
    const float* relk = (const float*)d_in[9];
    const float* relv = (const float*)d_in[10];
    float* out = (float*)d_out;

    float* ws = (float*)d_ws;
    float* q  = ws;  ws += (size_t)B * NQ * DM;   // 268 MB
    float* kt = ws;  ws += (size_t)B * TL * DM;   // 20 MB
    float* vt = ws;  ws += (size_t)B * TL * DM;   // 20 MB
    float* ki = ws;  ws += (size_t)B * IL * DM;   // 67 MB
    float* vi = ws;  ws += (size_t)B * IL * DM;   // 67 MB
    float* oi = ws;  ws += (size_t)B * NQ * DM;   // 268 MB

    const long long ctx_stride = (long long)(TL + IL) * DM;
    dim3 blk(256);

    // projections
    gemm_kernel<<<dim3(16, (B * NQ) / 64), blk, 0, stream>>>(
        x, Wq, nullptr, q, B * NQ, 0, 0, DM, DM);
    gemm_kernel<<<dim3(16, (B * TL) / 64), blk, 0, stream>>>(
        ctx, Wk, nullptr, kt, TL, ctx_stride, 0, DM, DM);
    gemm_kernel<<<dim3(16, (B * TL) / 64), blk, 0, stream>>>(
        ctx, Wv, nullptr, vt, TL, ctx_stride, 0, DM, DM);
    gemm_kernel<<<dim3(16, (B * IL) / 64), blk, 0, stream>>>(
        ctx, Wkip, nullptr, ki, IL, ctx_stride, TL, DM, DM);
    gemm_kernel<<<dim3(16, (B * IL) / 64), blk, 0, stream>>>(
        ctx, Wvip, nullptr, vi, IL, ctx_stride, TL, DM, DM);

    // fused attention (text + rel + image) -> out_inner
    attn_kernel<<<dim3(NQ / 64, B * H), blk, 0, stream>>>(
        q, kt, vt, ki, vi, relk, relv, oi);

    // output projection + bias
    gemm_kernel<<<dim3(16, (B * NQ) / 64), blk, 0, stream>>>(
        oi, Wout, bout, out, B * NQ, 0, 0, DM, DM);
}